// Round 15
// baseline (749.213 us; speedup 1.0000x reference)
//
#include <hip/hip_runtime.h>

#define B_ 32
#define N_ 4096
#define D_ 512
#define S_ 8
#define ITERS_ 3

__device__ __forceinline__ float sigmoid_f(float x) {
    return 1.0f / (1.0f + __expf(-x));
}
__device__ __forceinline__ float tanh_f(float x) {
    float e = __expf(2.0f * x);
    return 1.0f - 2.0f / (e + 1.0f);
}

// ---------------------------------------------------------------- shared GEMM tile body
template<int WT, int LNA>
__device__ void gemm_body(const float* __restrict__ A, const float* __restrict__ W,
                          const float* __restrict__ bias, float* __restrict__ C,
                          int M, int N, int K, int bxi, int byi,
                          const float* __restrict__ stats,
                          const float* __restrict__ lng, const float* __restrict__ lnb,
                          float* smem) {
    float (*As)[68] = (float (*)[68])smem;
    float (*Ws)[36] = (float (*)[36])(smem + 64 * 68);
    int t  = threadIdx.x;
    int bm = byi * 64, bn = bxi * 32;
    int tm = t >> 4, tn = t & 15;
    float acc[4][2] = {{0.f,0.f},{0.f,0.f},{0.f,0.f},{0.f,0.f}};

    for (int kk = 0; kk < K; kk += 64) {
        __syncthreads();
        if (WT == 2) {
#pragma unroll
            for (int r = 0; r < 4; ++r) {
                int idx = t + r * 256;
                int k = idx >> 4, m4 = idx & 15;
                float4 a4 = *(const float4*)(A + (size_t)(kk + k) * M + bm + (m4 << 2));
                *(float4*)&As[k][m4 << 2] = a4;
            }
        } else {
#pragma unroll
            for (int r = 0; r < 4; ++r) {
                int flat = t * 4 + r * 1024;
                int m = flat >> 6, k = flat & 63;
                float4 a4 = *(const float4*)(A + (size_t)(bm + m) * K + kk + k);
                if (LNA) {
                    float mean = stats[(bm + m) * 2];
                    float rs   = stats[(bm + m) * 2 + 1];
                    float4 g4 = *(const float4*)(lng + kk + k);
                    float4 b4 = *(const float4*)(lnb + kk + k);
                    a4.x = fmaf((a4.x - mean) * rs, g4.x, b4.x);
                    a4.y = fmaf((a4.y - mean) * rs, g4.y, b4.y);
                    a4.z = fmaf((a4.z - mean) * rs, g4.z, b4.z);
                    a4.w = fmaf((a4.w - mean) * rs, g4.w, b4.w);
                }
                As[k + 0][m] = a4.x; As[k + 1][m] = a4.y;
                As[k + 2][m] = a4.z; As[k + 3][m] = a4.w;
            }
        }
        if (WT == 1) {
#pragma unroll
            for (int r = 0; r < 2; ++r) {
                int flat = t * 4 + r * 1024;
                int n = flat >> 6, k = flat & 63;
                float4 w4 = *(const float4*)(W + (size_t)(bn + n) * K + kk + k);
                Ws[k + 0][n] = w4.x; Ws[k + 1][n] = w4.y;
                Ws[k + 2][n] = w4.z; Ws[k + 3][n] = w4.w;
            }
        } else {
#pragma unroll
            for (int r = 0; r < 2; ++r) {
                int flat = t * 4 + r * 1024;
                int k = flat >> 5, n = flat & 31;
                float4 w4 = *(const float4*)(W + (size_t)(kk + k) * N + bn + n);
                *(float4*)&Ws[k][n] = w4;
            }
        }
        __syncthreads();
#pragma unroll
        for (int k = 0; k < 64; ++k) {
            float4 a = *(const float4*)&As[k][tm << 2];
            float2 w = *(const float2*)&Ws[k][tn << 1];
            acc[0][0] = fmaf(a.x, w.x, acc[0][0]); acc[0][1] = fmaf(a.x, w.y, acc[0][1]);
            acc[1][0] = fmaf(a.y, w.x, acc[1][0]); acc[1][1] = fmaf(a.y, w.y, acc[1][1]);
            acc[2][0] = fmaf(a.z, w.x, acc[2][0]); acc[2][1] = fmaf(a.z, w.y, acc[2][1]);
            acc[3][0] = fmaf(a.w, w.x, acc[3][0]); acc[3][1] = fmaf(a.w, w.y, acc[3][1]);
        }
    }
#pragma unroll
    for (int i = 0; i < 4; ++i) {
#pragma unroll
        for (int j = 0; j < 2; ++j) {
            int row = bm + (tm << 2) + i;
            int col = bn + (tn << 1) + j;
            float v = acc[i][j];
            if (bias) v += bias[col];
            C[(size_t)row * N + col] = v;
        }
    }
}

// ---------------------------------------------------------------- slot init body
__device__ void init_body(const float* __restrict__ noise, const float* __restrict__ mu,
                          const float* __restrict__ sg, float* __restrict__ slots,
                          float* __restrict__ stats, int blk) {
    int wid = threadIdx.x >> 6, lane = threadIdx.x & 63;
    int row = blk * 4 + wid;
    const float4* nz = (const float4*)(noise + (size_t)row * D_);
    const float4* m4 = (const float4*)(mu + (size_t)(row & 7) * D_);
    const float4* s4 = (const float4*)(sg + (size_t)(row & 7) * D_);
    float4 v0 = nz[lane], v1 = nz[64 + lane];
    float4 a0 = m4[lane], a1 = m4[64 + lane];
    float4 c0 = s4[lane], c1 = s4[64 + lane];
    v0.x = fmaf(c0.x, v0.x, a0.x); v0.y = fmaf(c0.y, v0.y, a0.y);
    v0.z = fmaf(c0.z, v0.z, a0.z); v0.w = fmaf(c0.w, v0.w, a0.w);
    v1.x = fmaf(c1.x, v1.x, a1.x); v1.y = fmaf(c1.y, v1.y, a1.y);
    v1.z = fmaf(c1.z, v1.z, a1.z); v1.w = fmaf(c1.w, v1.w, a1.w);
    float4* o4 = (float4*)(slots + (size_t)row * D_);
    o4[lane] = v0; o4[64 + lane] = v1;
    float s1 = v0.x + v0.y + v0.z + v0.w + v1.x + v1.y + v1.z + v1.w;
    float s2 = v0.x*v0.x; s2 = fmaf(v0.y,v0.y,s2); s2 = fmaf(v0.z,v0.z,s2); s2 = fmaf(v0.w,v0.w,s2);
    s2 = fmaf(v1.x,v1.x,s2); s2 = fmaf(v1.y,v1.y,s2); s2 = fmaf(v1.z,v1.z,s2); s2 = fmaf(v1.w,v1.w,s2);
#pragma unroll
    for (int off = 32; off > 0; off >>= 1) {
        s1 += __shfl_xor(s1, off, 64);
        s2 += __shfl_xor(s2, off, 64);
    }
    if (lane == 0) {
        float mean = s1 * (1.0f / D_);
        float var  = s2 * (1.0f / D_) - mean * mean;
        stats[row * 2]     = mean;
        stats[row * 2 + 1] = rsqrtf(var + 1e-5f);
    }
}

// ---------------------------------------------------------------- merged prologue
__global__ __launch_bounds__(256) void k_pro(const float* __restrict__ wk, const float* __restrict__ wq,
                                             const float* __restrict__ w_ih, const float* __restrict__ wv,
                                             float* __restrict__ Mqk, float* __restrict__ Wiv,
                                             const float* __restrict__ noise, const float* __restrict__ mu,
                                             const float* __restrict__ sg, float* __restrict__ slots,
                                             float* __restrict__ stats) {
    __shared__ float smem[64 * 68 + 64 * 36];
    int blk = blockIdx.x;
    if (blk < 128) {
        gemm_body<2,0>(wk, wq, nullptr, Mqk, 512, 512, 512, blk & 15, blk >> 4,
                       nullptr, nullptr, nullptr, smem);
    } else if (blk < 512) {
        int t2 = blk - 128;
        gemm_body<0,0>(w_ih, wv, nullptr, Wiv, 1536, 512, 512, t2 & 15, t2 >> 4,
                       nullptr, nullptr, nullptr, smem);
    } else {
        init_body(noise, mu, sg, slots, stats, blk - 512);
    }
}

// ---------------------------------------------------------------- generic small GEMM kernel
template<int WT, int LNA>
__global__ __launch_bounds__(256) void k_gemm(const float* __restrict__ A, const float* __restrict__ W,
                                              const float* __restrict__ bias, float* __restrict__ C,
                                              int M, int N, int K,
                                              const float* __restrict__ stats,
                                              const float* __restrict__ lng, const float* __restrict__ lnb) {
    __shared__ float smem[64 * 68 + 64 * 36];
    gemm_body<WT,LNA>(A, W, bias, C, M, N, K, blockIdx.x, blockIdx.y, stats, lng, lnb, smem);
}

// ---------------------------------------------------------------- fused attention v9 + gh prelude (R13, verified)
template<int FIRST>
__global__ __launch_bounds__(512, 1) void k_attn_gh(const float* __restrict__ x,
                                                    const float* __restrict__ qk,
                                                    const float* __restrict__ g,
                                                    const float* __restrict__ bvec,
                                                    float* __restrict__ part,
                                                    float* __restrict__ bsum,
                                                    float2* __restrict__ murs,
                                                    const float* __restrict__ slots,
                                                    const float* __restrict__ w_hh,
                                                    const float* __restrict__ b_hh,
                                                    float* __restrict__ gg) {
    __shared__ float smem[8704];
    const int blk = blockIdx.x;
    const int t = threadIdx.x;

    if (blk < 96) {
        // ---------------- gh GEMM prelude: 64x64 tile, 512 threads
        const int ci = blk % 24, ri = blk / 24;
        const int bm = ri * 64, bn = ci * 64;
        float (*As)[68] = (float (*)[68])smem;
        float (*Ws)[68] = (float (*)[68])(smem + 64 * 68);
        const int tm = t >> 5, tn = t & 31;
        float acc[4][2] = {{0.f,0.f},{0.f,0.f},{0.f,0.f},{0.f,0.f}};
        for (int kk = 0; kk < 512; kk += 64) {
            __syncthreads();
#pragma unroll
            for (int r = 0; r < 2; ++r) {
                int flat = t * 4 + r * 2048;
                int m = flat >> 6, k = flat & 63;
                float4 a4 = *(const float4*)(slots + (size_t)(bm + m) * 512 + kk + k);
                As[k + 0][m] = a4.x; As[k + 1][m] = a4.y;
                As[k + 2][m] = a4.z; As[k + 3][m] = a4.w;
            }
#pragma unroll
            for (int r = 0; r < 2; ++r) {
                int flat = t * 4 + r * 2048;
                int n = flat >> 6, k = flat & 63;
                float4 w4 = *(const float4*)(w_hh + (size_t)(bn + n) * 512 + kk + k);
                Ws[k + 0][n] = w4.x; Ws[k + 1][n] = w4.y;
                Ws[k + 2][n] = w4.z; Ws[k + 3][n] = w4.w;
            }
            __syncthreads();
#pragma unroll
            for (int k = 0; k < 64; ++k) {
                const float4 a = *(const float4*)&As[k][tm << 2];
                const float2 w = *(const float2*)&Ws[k][tn << 1];
                acc[0][0] = fmaf(a.x, w.x, acc[0][0]); acc[0][1] = fmaf(a.x, w.y, acc[0][1]);
                acc[1][0] = fmaf(a.y, w.x, acc[1][0]); acc[1][1] = fmaf(a.y, w.y, acc[1][1]);
                acc[2][0] = fmaf(a.z, w.x, acc[2][0]); acc[2][1] = fmaf(a.z, w.y, acc[2][1]);
                acc[3][0] = fmaf(a.w, w.x, acc[3][0]); acc[3][1] = fmaf(a.w, w.y, acc[3][1]);
            }
        }
#pragma unroll
        for (int i = 0; i < 4; ++i) {
#pragma unroll
            for (int j = 0; j < 2; ++j) {
                int row = bm + (tm << 2) + i;
                int col = bn + (tn << 1) + j;
                gg[(size_t)row * 3072 + col] = acc[i][j] + b_hh[col];
            }
        }
        __syncthreads();
    }

    // ---------------- attention (ALL 256 blocks)
    float* qts  = smem;
    float* dds  = smem + 4096;
    float* wls  = smem + 4480;
    float* mur  = smem + 4864;
    float* redA = smem + 5888;
    float* redB = smem + 5952;
    float* c12  = smem + 6016;
    float* u0s  = smem;
    const int nc = blk & 7, b = blk >> 3;
    const int w = t >> 6, lane = t & 63;
    const size_t rowbase = (size_t)b * N_ + (size_t)nc * 512;

    {
        const float4* qk4 = (const float4*)(qk + (size_t)b * 4096);
        const float4* g4 = (const float4*)g;
        const float4* b4 = (const float4*)bvec;
        float c1p[2], c2p[2];
#pragma unroll
        for (int r = 0; r < 2; ++r) {
            int f = t + r * 512;
            int k4 = f & 127, sidx = f >> 7;
            float4 v = qk4[f];
            float4 gg4 = g4[k4];
            float4 bb = b4[k4];
            float4 qv = make_float4(v.x*gg4.x, v.y*gg4.y, v.z*gg4.z, v.w*gg4.w);
            *(float4*)&qts[(k4 * 8 + (sidx ^ (k4 & 7))) * 4] = qv;
            c1p[r] = qv.x + qv.y + qv.z + qv.w;
            c2p[r] = bb.x*v.x + bb.y*v.y + bb.z*v.z + bb.w*v.w;
        }
#pragma unroll
        for (int off = 32; off > 0; off >>= 1) {
#pragma unroll
            for (int r = 0; r < 2; ++r) {
                c1p[r] += __shfl_xor(c1p[r], off, 64);
                c2p[r] += __shfl_xor(c2p[r], off, 64);
            }
        }
        if (lane == 0) {
            redA[w * 2 + 0] = c1p[0]; redA[w * 2 + 1] = c1p[1];
            redB[w * 2 + 0] = c2p[0]; redB[w * 2 + 1] = c2p[1];
        }
    }
    if (!FIRST) {
        float2 mm = murs[rowbase + t];
        mur[2 * t] = mm.x; mur[2 * t + 1] = mm.y;
    }
    __syncthreads();
    if (t < 8) {
        int s = t;
        float v1, v2;
        if (s < 4) { v1 = redA[4*s]       + redA[4*s + 2];     v2 = redB[4*s]       + redB[4*s + 2]; }
        else       { v1 = redA[4*(s-4)+1] + redA[4*(s-4)+3];   v2 = redB[4*(s-4)+1] + redB[4*(s-4)+3]; }
        c12[s] = v1; c12[8 + s] = v2;
    }
    __syncthreads();

    float4 qa[8], qb[8];
#pragma unroll
    for (int s = 0; s < 8; ++s) {
        qa[s] = *(const float4*)&qts[(lane * 8 + (s ^ (lane & 7))) * 4];
        qb[s] = *(const float4*)&qts[((64 + lane) * 8 + (s ^ (lane & 7))) * 4];
    }

    const bool hb5 = (lane & 32) != 0, hb4 = (lane & 16) != 0, hb3 = (lane & 8) != 0;
    const float cnorm = 1.0f / (1.0f + 8.0f * 1e-8f);
    const float eadd  = 1e-8f * cnorm;

    float4 acc0[8], acc1[8];
#pragma unroll
    for (int s = 0; s < 8; ++s) {
        acc0[s] = make_float4(0.f, 0.f, 0.f, 0.f);
        acc1[s] = make_float4(0.f, 0.f, 0.f, 0.f);
    }
    float aS8[8] = {0,0,0,0,0,0,0,0}, tS8[8] = {0,0,0,0,0,0,0,0};

    const float4* xg = (const float4*)(x + rowbase * D_);
    float4 cur[8], nxt[8];
    {
        int r0 = w * 4;
#pragma unroll
        for (int i = 0; i < 4; ++i) {
            cur[2*i]   = xg[(size_t)(r0 + i) * 128 + lane];
            cur[2*i+1] = xg[(size_t)(r0 + i) * 128 + 64 + lane];
        }
    }

    for (int jb = 0; jb < 16; ++jb) {
        {
            int jn = (jb < 15) ? jb + 1 : 15;
            int r0 = jn * 32 + w * 4;
#pragma unroll
            for (int i = 0; i < 4; ++i) {
                nxt[2*i]   = xg[(size_t)(r0 + i) * 128 + lane];
                nxt[2*i+1] = xg[(size_t)(r0 + i) * 128 + 64 + lane];
            }
        }
#pragma unroll
        for (int i = 0; i < 4; ++i) {
            float4 xa = cur[2*i], xb = cur[2*i+1];
            float dd[8];
#pragma unroll
            for (int s = 0; s < 8; ++s) {
                float td = xa.x * qa[s].x;
                td = fmaf(xa.y, qa[s].y, td); td = fmaf(xa.z, qa[s].z, td); td = fmaf(xa.w, qa[s].w, td);
                td = fmaf(xb.x, qb[s].x, td); td = fmaf(xb.y, qb[s].y, td);
                td = fmaf(xb.z, qb[s].z, td); td = fmaf(xb.w, qb[s].w, td);
                dd[s] = td;
            }
            float r4[4];
#pragma unroll
            for (int s = 0; s < 4; ++s) {
                float snd = hb5 ? dd[s] : dd[s + 4];
                float kp  = hb5 ? dd[s + 4] : dd[s];
                r4[s] = kp + __shfl_xor(snd, 32, 64);
            }
            float r2v[2];
#pragma unroll
            for (int s = 0; s < 2; ++s) {
                float snd = hb4 ? r4[s] : r4[s + 2];
                float kp  = hb4 ? r4[s + 2] : r4[s];
                r2v[s] = kp + __shfl_xor(snd, 16, 64);
            }
            float v;
            {
                float snd = hb3 ? r2v[0] : r2v[1];
                float kp  = hb3 ? r2v[1] : r2v[0];
                v = kp + __shfl_xor(snd, 8, 64);
            }
            v += __shfl_xor(v, 4, 64);
            v += __shfl_xor(v, 2, 64);
            v += __shfl_xor(v, 1, 64);
            int rb = w * 4 + i;
            if ((lane & 7) == 0) dds[rb * 12 + (lane >> 3)] = v;

            if (FIRST) {
                float sx = xa.x + xa.y + xa.z + xa.w + xb.x + xb.y + xb.z + xb.w;
                float sxx = xa.x*xa.x; sxx = fmaf(xa.y,xa.y,sxx); sxx = fmaf(xa.z,xa.z,sxx); sxx = fmaf(xa.w,xa.w,sxx);
                sxx = fmaf(xb.x,xb.x,sxx); sxx = fmaf(xb.y,xb.y,sxx); sxx = fmaf(xb.z,xb.z,sxx); sxx = fmaf(xb.w,xb.w,sxx);
#pragma unroll
                for (int off = 32; off > 0; off >>= 1) {
                    sx  += __shfl_xor(sx, off, 64);
                    sxx += __shfl_xor(sxx, off, 64);
                }
                float mean = sx * (1.0f / D_);
                float rs   = rsqrtf(sxx * (1.0f / D_) - mean * mean + 1e-5f);
                if (lane == 0) {
                    int br = jb * 32 + rb;
                    mur[br * 2] = mean; mur[br * 2 + 1] = rs;
                    murs[rowbase + br] = make_float2(mean, rs);
                }
            }
        }
        if (lane < 4) {
            int rb = w * 4 + lane;
            int br = jb * 32 + rb;
            float4 d03 = *(const float4*)&dds[rb * 12];
            float4 d47 = *(const float4*)&dds[rb * 12 + 4];
            float mean = mur[br * 2], rs = mur[br * 2 + 1];
            float mc = -rs * mean;
            float lg[8];
            lg[0] = fmaf(rs, d03.x, fmaf(mc, c12[0], c12[8]));
            lg[1] = fmaf(rs, d03.y, fmaf(mc, c12[1], c12[9]));
            lg[2] = fmaf(rs, d03.z, fmaf(mc, c12[2], c12[10]));
            lg[3] = fmaf(rs, d03.w, fmaf(mc, c12[3], c12[11]));
            lg[4] = fmaf(rs, d47.x, fmaf(mc, c12[4], c12[12]));
            lg[5] = fmaf(rs, d47.y, fmaf(mc, c12[5], c12[13]));
            lg[6] = fmaf(rs, d47.z, fmaf(mc, c12[6], c12[14]));
            lg[7] = fmaf(rs, d47.w, fmaf(mc, c12[7], c12[15]));
            float mx = lg[0];
#pragma unroll
            for (int s = 1; s < 8; ++s) mx = fmaxf(mx, lg[s]);
            float p[8], psum = 0.f;
#pragma unroll
            for (int s = 0; s < 8; ++s) { p[s] = __expf(lg[s] - mx); psum += p[s]; }
            float ip = cnorm / psum;
            float wv[8];
#pragma unroll
            for (int s = 0; s < 8; ++s) {
                float a = fmaf(p[s], ip, eadd);
                wv[s] = a * rs;
                aS8[s] += a;
                tS8[s] = fmaf(wv[s], mean, tS8[s]);
            }
            *(float4*)&wls[rb * 12]     = make_float4(wv[0], wv[1], wv[2], wv[3]);
            *(float4*)&wls[rb * 12 + 4] = make_float4(wv[4], wv[5], wv[6], wv[7]);
        }
#pragma unroll
        for (int i = 0; i < 4; ++i) {
            int rb = w * 4 + i;
            float4 w03 = *(const float4*)&wls[rb * 12];
            float4 w47 = *(const float4*)&wls[rb * 12 + 4];
            float4 xa = cur[2*i], xb = cur[2*i+1];
            acc0[0].x = fmaf(w03.x, xa.x, acc0[0].x); acc0[0].y = fmaf(w03.x, xa.y, acc0[0].y);
            acc0[0].z = fmaf(w03.x, xa.z, acc0[0].z); acc0[0].w = fmaf(w03.x, xa.w, acc0[0].w);
            acc1[0].x = fmaf(w03.x, xb.x, acc1[0].x); acc1[0].y = fmaf(w03.x, xb.y, acc1[0].y);
            acc1[0].z = fmaf(w03.x, xb.z, acc1[0].z); acc1[0].w = fmaf(w03.x, xb.w, acc1[0].w);
            acc0[1].x = fmaf(w03.y, xa.x, acc0[1].x); acc0[1].y = fmaf(w03.y, xa.y, acc0[1].y);
            acc0[1].z = fmaf(w03.y, xa.z, acc0[1].z); acc0[1].w = fmaf(w03.y, xa.w, acc0[1].w);
            acc1[1].x = fmaf(w03.y, xb.x, acc1[1].x); acc1[1].y = fmaf(w03.y, xb.y, acc1[1].y);
            acc1[1].z = fmaf(w03.y, xb.z, acc1[1].z); acc1[1].w = fmaf(w03.y, xb.w, acc1[1].w);
            acc0[2].x = fmaf(w03.z, xa.x, acc0[2].x); acc0[2].y = fmaf(w03.z, xa.y, acc0[2].y);
            acc0[2].z = fmaf(w03.z, xa.z, acc0[2].z); acc0[2].w = fmaf(w03.z, xa.w, acc0[2].w);
            acc1[2].x = fmaf(w03.z, xb.x, acc1[2].x); acc1[2].y = fmaf(w03.z, xb.y, acc1[2].y);
            acc1[2].z = fmaf(w03.z, xb.z, acc1[2].z); acc1[2].w = fmaf(w03.z, xb.w, acc1[2].w);
            acc0[3].x = fmaf(w03.w, xa.x, acc0[3].x); acc0[3].y = fmaf(w03.w, xa.y, acc0[3].y);
            acc0[3].z = fmaf(w03.w, xa.z, acc0[3].z); acc0[3].w = fmaf(w03.w, xa.w, acc0[3].w);
            acc1[3].x = fmaf(w03.w, xb.x, acc1[3].x); acc1[3].y = fmaf(w03.w, xb.y, acc1[3].y);
            acc1[3].z = fmaf(w03.w, xb.z, acc1[3].z); acc1[3].w = fmaf(w03.w, xb.w, acc1[3].w);
            acc0[4].x = fmaf(w47.x, xa.x, acc0[4].x); acc0[4].y = fmaf(w47.x, xa.y, acc0[4].y);
            acc0[4].z = fmaf(w47.x, xa.z, acc0[4].z); acc0[4].w = fmaf(w47.x, xa.w, acc0[4].w);
            acc1[4].x = fmaf(w47.x, xb.x, acc1[4].x); acc1[4].y = fmaf(w47.x, xb.y, acc1[4].y);
            acc1[4].z = fmaf(w47.x, xb.z, acc1[4].z); acc1[4].w = fmaf(w47.x, xb.w, acc1[4].w);
            acc0[5].x = fmaf(w47.y, xa.x, acc0[5].x); acc0[5].y = fmaf(w47.y, xa.y, acc0[5].y);
            acc0[5].z = fmaf(w47.y, xa.z, acc0[5].z); acc0[5].w = fmaf(w47.y, xa.w, acc0[5].w);
            acc1[5].x = fmaf(w47.y, xb.x, acc1[5].x); acc1[5].y = fmaf(w47.y, xb.y, acc1[5].y);
            acc1[5].z = fmaf(w47.y, xb.z, acc1[5].z); acc1[5].w = fmaf(w47.y, xb.w, acc1[5].w);
            acc0[6].x = fmaf(w47.z, xa.x, acc0[6].x); acc0[6].y = fmaf(w47.z, xa.y, acc0[6].y);
            acc0[6].z = fmaf(w47.z, xa.z, acc0[6].z); acc0[6].w = fmaf(w47.z, xa.w, acc0[6].w);
            acc1[6].x = fmaf(w47.z, xb.x, acc1[6].x); acc1[6].y = fmaf(w47.z, xb.y, acc1[6].y);
            acc1[6].z = fmaf(w47.z, xb.z, acc1[6].z); acc1[6].w = fmaf(w47.z, xb.w, acc1[6].w);
            acc0[7].x = fmaf(w47.w, xa.x, acc0[7].x); acc0[7].y = fmaf(w47.w, xa.y, acc0[7].y);
            acc0[7].z = fmaf(w47.w, xa.z, acc0[7].z); acc0[7].w = fmaf(w47.w, xa.w, acc0[7].w);
            acc1[7].x = fmaf(w47.w, xb.x, acc1[7].x); acc1[7].y = fmaf(w47.w, xb.y, acc1[7].y);
            acc1[7].z = fmaf(w47.w, xb.z, acc1[7].z); acc1[7].w = fmaf(w47.w, xb.w, acc1[7].w);
        }
#pragma unroll
        for (int i = 0; i < 8; ++i) cur[i] = nxt[i];
    }

#pragma unroll
    for (int s = 0; s < 8; ++s) {
        aS8[s] += __shfl_xor(aS8[s], 1, 64);
        aS8[s] += __shfl_xor(aS8[s], 2, 64);
        tS8[s] += __shfl_xor(tS8[s], 1, 64);
        tS8[s] += __shfl_xor(tS8[s], 2, 64);
    }
    if (lane == 0) {
#pragma unroll
        for (int s = 0; s < 8; ++s) { redA[w * 8 + s] = aS8[s]; redB[w * 8 + s] = tS8[s]; }
    }
    for (int w2 = 0; w2 < 8; ++w2) {
        if (w == w2) {
#pragma unroll
            for (int s = 0; s < 8; ++s) {
                float* p0 = &u0s[s * 512 + (lane << 2)];
                float* p1 = p0 + 256;
                if (w2 == 0) {
                    *(float4*)p0 = acc0[s];
                    *(float4*)p1 = acc1[s];
                } else {
                    float4 v0 = *(float4*)p0;
                    v0.x += acc0[s].x; v0.y += acc0[s].y; v0.z += acc0[s].z; v0.w += acc0[s].w;
                    *(float4*)p0 = v0;
                    float4 v1 = *(float4*)p1;
                    v1.x += acc1[s].x; v1.y += acc1[s].y; v1.z += acc1[s].z; v1.w += acc1[s].w;
                    *(float4*)p1 = v1;
                }
            }
        }
        __syncthreads();
    }
    if (t < 16) {
        int s = t & 7;
        const float* src = (t < 8) ? redA : redB;
        float v = 0.f;
#pragma unroll
        for (int w2 = 0; w2 < 8; ++w2) v += src[w2 * 8 + s];
        bsum[(size_t)(b * 8 + nc) * 16 + t] = v;
    }
    float4* d4 = (float4*)(part + (size_t)(b * 8 + nc) * 4096);
    const float4* s4 = (const float4*)u0s;
    d4[t] = s4[t];
    d4[t + 512] = s4[t + 512];
}

// ---------------------------------------------------------------- gi GEMM (fused u0-reduce + affine correction)
// A[row][d] = g[d] * (sum_nc part[...] - Tv(row)) + Av(row) * bvec[d]  — replicates k_ured bitwise.
__global__ __launch_bounds__(256) void k_gi(const float* __restrict__ part,
                                            const float* __restrict__ bsum,
                                            const float* __restrict__ lng,
                                            const float* __restrict__ lnb,
                                            const float* __restrict__ Wiv,
                                            const float* __restrict__ b_ih,
                                            float* __restrict__ gg) {
    __shared__ float As[64][68];
    __shared__ float Ws[64][36];
    const int t = threadIdx.x;
    const int bn = blockIdx.x * 32;
    const int bm = blockIdx.y * 64;
    int tm = t >> 4, tn = t & 15;
    float acc[4][2] = {{0.f,0.f},{0.f,0.f},{0.f,0.f},{0.f,0.f}};

    // per-thread row constants (rows m = t>>4 + 16r)
    float Avr[4], Tvr[4];
#pragma unroll
    for (int r = 0; r < 4; ++r) {
        int row = bm + (t >> 4) + 16 * r;
        int bb8 = row & ~7, s = row & 7;
        float Av = 0.f, Tv = 0.f;
#pragma unroll
        for (int nc = 0; nc < 8; ++nc) {
            Av += bsum[(size_t)(bb8 + nc) * 16 + s];
            Tv += bsum[(size_t)(bb8 + nc) * 16 + 8 + s];
        }
        Avr[r] = Av; Tvr[r] = Tv;
    }

    for (int kk = 0; kk < 512; kk += 64) {
        __syncthreads();
#pragma unroll
        for (int r = 0; r < 4; ++r) {
            int flat = t * 4 + r * 1024;
            int m = flat >> 6, k = flat & 63;
            int row = bm + m;
            const float* pb = part + (size_t)(row & ~7) * 4096 + (size_t)(row & 7) * 512 + kk + k;
            float4 a4 = *(const float4*)pb;
#pragma unroll
            for (int nc = 1; nc < 8; ++nc) {
                float4 v = *(const float4*)(pb + (size_t)nc * 4096);
                a4.x += v.x; a4.y += v.y; a4.z += v.z; a4.w += v.w;
            }
            float4 g4 = *(const float4*)(lng + kk + k);
            float4 b4 = *(const float4*)(lnb + kk + k);
            float Av = Avr[r], Tv = Tvr[r];
            a4.x = fmaf(g4.x, a4.x - Tv, Av * b4.x);
            a4.y = fmaf(g4.y, a4.y - Tv, Av * b4.y);
            a4.z = fmaf(g4.z, a4.z - Tv, Av * b4.z);
            a4.w = fmaf(g4.w, a4.w - Tv, Av * b4.w);
            As[k + 0][m] = a4.x; As[k + 1][m] = a4.y;
            As[k + 2][m] = a4.z; As[k + 3][m] = a4.w;
        }
#pragma unroll
        for (int r = 0; r < 2; ++r) {
            int flat = t * 4 + r * 1024;
            int n = flat >> 6, k = flat & 63;
            float4 w4 = *(const float4*)(Wiv + (size_t)(bn + n) * 512 + kk + k);
            Ws[k + 0][n] = w4.x; Ws[k + 1][n] = w4.y;
            Ws[k + 2][n] = w4.z; Ws[k + 3][n] = w4.w;
        }
        __syncthreads();
#pragma unroll
        for (int k = 0; k < 64; ++k) {
            float4 a = *(const float4*)&As[k][tm << 2];
            float2 w = *(const float2*)&Ws[k][tn << 1];
            acc[0][0] = fmaf(a.x, w.x, acc[0][0]); acc[0][1] = fmaf(a.x, w.y, acc[0][1]);
            acc[1][0] = fmaf(a.y, w.x, acc[1][0]); acc[1][1] = fmaf(a.y, w.y, acc[1][1]);
            acc[2][0] = fmaf(a.z, w.x, acc[2][0]); acc[2][1] = fmaf(a.z, w.y, acc[2][1]);
            acc[3][0] = fmaf(a.w, w.x, acc[3][0]); acc[3][1] = fmaf(a.w, w.y, acc[3][1]);
        }
    }
#pragma unroll
    for (int i = 0; i < 4; ++i) {
#pragma unroll
        for (int j = 0; j < 2; ++j) {
            int row = bm + (tm << 2) + i;
            int cw  = bn + (tn << 1) + j;
            gg[(size_t)row * 3072 + 1536 + cw] = acc[i][j] + b_ih[cw];
        }
    }
}

// ---------------------------------------------------------------- P2: GRU + MLP + LN + qk_next (R13, verified)
__global__ __launch_bounds__(512) void k_p2(const float* __restrict__ gg,
                                            const float* __restrict__ slots,
                                            const float* __restrict__ w1, const float* __restrict__ b1,
                                            const float* __restrict__ w2, const float* __restrict__ b2,
                                            const float* __restrict__ wqkT,
                                            const float* __restrict__ ln_m_g, const float* __restrict__ ln_m_b,
                                            const float* __restrict__ ln_s_g, const float* __restrict__ ln_s_b,
                                            float* __restrict__ dst, float* __restrict__ qkout, int last) {
    __shared__ float s2[512];
    __shared__ float t0[512];
    __shared__ float hh[512];
    __shared__ float red[16];
    __shared__ float stat[2];
    const int t = threadIdx.x;
    const int w = t >> 6, lane = t & 63;
    const size_t row = blockIdx.x;

    float s2v;
    {
        const float* ghb = gg + row * 3072;
        const float* gib = ghb + 1536;
        float gir = gib[t], giz = gib[t + 512], gin = gib[t + 1024];
        float ghr = ghb[t], ghz = ghb[t + 512], ghn = ghb[t + 1024];
        float rr = sigmoid_f(gir + ghr);
        float zz = sigmoid_f(giz + ghz);
        float nn = tanh_f(fmaf(rr, ghn, gin));
        float sp = slots[row * 512 + t];
        s2v = fmaf(1.0f - zz, nn, zz * sp);
        s2[t] = s2v;
    }
    {
        float s1 = s2v, sq = s2v * s2v;
#pragma unroll
        for (int off = 32; off > 0; off >>= 1) {
            s1 += __shfl_xor(s1, off, 64);
            sq += __shfl_xor(sq, off, 64);
        }
        if (lane == 0) { red[w] = s1; red[8 + w] = sq; }
        __syncthreads();
        if (t == 0) {
            float t1 = 0.f, t2 = 0.f;
#pragma unroll
            for (int i = 0; i < 8; ++i) { t1 += red[i]; t2 += red[8 + i]; }
            float mean = t1 * (1.0f / D_);
            stat[0] = mean;
            stat[1] = rsqrtf(t2 * (1.0f / D_) - mean * mean + 1e-5f);
        }
        __syncthreads();
    }
    t0[t] = fmaf((s2v - stat[0]) * stat[1], ln_m_g[t], ln_m_b[t]);
    __syncthreads();
    {
        const float4* wr = (const float4*)(w1 + (size_t)t * 512);
        float a = 0.f;
#pragma unroll 8
        for (int k4 = 0; k4 < 128; ++k4) {
            float4 w4 = wr[k4];
            float4 q0 = *(const float4*)&t0[k4 << 2];
            a = fmaf(q0.x, w4.x, a); a = fmaf(q0.y, w4.y, a);
            a = fmaf(q0.z, w4.z, a); a = fmaf(q0.w, w4.w, a);
        }
        hh[t] = fmaxf(a + b1[t], 0.f);
    }
    __syncthreads();
    float ov;
    {
        const float4* wr = (const float4*)(w2 + (size_t)t * 512);
        float a = 0.f;
#pragma unroll 8
        for (int k4 = 0; k4 < 128; ++k4) {
            float4 w4 = wr[k4];
            float4 q0 = *(const float4*)&hh[k4 << 2];
            a = fmaf(q0.x, w4.x, a); a = fmaf(q0.y, w4.y, a);
            a = fmaf(q0.z, w4.z, a); a = fmaf(q0.w, w4.w, a);
        }
        ov = s2[t] + a + b2[t];
        dst[row * 512 + t] = ov;
    }
    if (last) return;
    {
        float s1 = ov, sq = ov * ov;
#pragma unroll
        for (int off = 32; off > 0; off >>= 1) {
            s1 += __shfl_xor(s1, off, 64);
            sq += __shfl_xor(sq, off, 64);
        }
        if (lane == 0) { red[w] = s1; red[8 + w] = sq; }
        __syncthreads();
        if (t == 0) {
            float t1 = 0.f, t2 = 0.f;
#pragma unroll
            for (int i = 0; i < 8; ++i) { t1 += red[i]; t2 += red[8 + i]; }
            float mean = t1 * (1.0f / D_);
            stat[0] = mean;
            stat[1] = rsqrtf(t2 * (1.0f / D_) - mean * mean + 1e-5f);
        }
        __syncthreads();
    }
    t0[t] = fmaf((ov - stat[0]) * stat[1], ln_s_g[t], ln_s_b[t]);
    __syncthreads();
    {
        const float4* wr = (const float4*)(wqkT + (size_t)t * 512);
        float a = 0.f;
#pragma unroll 8
        for (int k4 = 0; k4 < 128; ++k4) {
            float4 w4 = wr[k4];
            float4 q0 = *(const float4*)&t0[k4 << 2];
            a = fmaf(q0.x, w4.x, a); a = fmaf(q0.y, w4.y, a);
            a = fmaf(q0.z, w4.z, a); a = fmaf(q0.w, w4.w, a);
        }
        qkout[row * 512 + t] = a;
    }
}

// ---------------------------------------------------------------- launch
extern "C" void kernel_launch(void* const* d_in, const int* in_sizes, int n_in,
                              void* d_out, int out_size, void* d_ws, size_t ws_size,
                              hipStream_t stream) {
    const float* inputs  = (const float*)d_in[0];
    const float* noise   = (const float*)d_in[1];
    const float* mu      = (const float*)d_in[2];
    const float* sg      = (const float*)d_in[3];
    const float* ln_in_g = (const float*)d_in[4];
    const float* ln_in_b = (const float*)d_in[5];
    const float* ln_s_g  = (const float*)d_in[6];
    const float* ln_s_b  = (const float*)d_in[7];
    const float* wq      = (const float*)d_in[8];
    const float* wk      = (const float*)d_in[9];
    const float* wv      = (const float*)d_in[10];
    const float* w_ih    = (const float*)d_in[11];
    const float* w_hh    = (const float*)d_in[12];
    const float* b_ih    = (const float*)d_in[13];
    const float* b_hh    = (const float*)d_in[14];
    const float* ln_m_g  = (const float*)d_in[15];
    const float* ln_m_b  = (const float*)d_in[16];
    const float* w1      = (const float*)d_in[17];
    const float* b1      = (const float*)d_in[18];
    const float* w2      = (const float*)d_in[19];
    const float* b2      = (const float*)d_in[20];

    float* ws = (float*)d_ws;
    const size_t SLOT = (size_t)B_ * S_ * D_;      // 131072
    size_t o = 0;
    float* slots = ws + o; o += SLOT;
    float* qk    = ws + o; o += SLOT;
    float* gg    = ws + o; o += (size_t)256 * 3072;
    float* Mqk   = ws + o; o += (size_t)D_ * D_;
    float* Wiv   = ws + o; o += (size_t)3 * D_ * D_;
    float* statsS= ws + o; o += 512;
    float* part  = ws + o; o += (size_t)8 * B_ * 4096;
    float* bsum  = ws + o; o += (size_t)B_ * 8 * 16;
    float2* murs = (float2*)(ws + o); o += (size_t)2 * B_ * N_;

    // ---- prologue (2 dispatches)
    k_pro<<<576, 256, 0, stream>>>(wk, wq, w_ih, wv, Mqk, Wiv, noise, mu, sg, slots, statsS);
    k_gemm<1,1><<<dim3(16, 4), 256, 0, stream>>>(slots, Mqk, nullptr, qk,
                                                 256, 512, 512, statsS, ln_s_g, ln_s_b);

    for (int it = 0; it < ITERS_; ++it) {
        if (it == 0)
            k_attn_gh<1><<<256, 512, 0, stream>>>(inputs, qk, ln_in_g, ln_in_b, part, bsum,
                                                  murs, slots, w_hh, b_hh, gg);
        else
            k_attn_gh<0><<<256, 512, 0, stream>>>(inputs, qk, ln_in_g, ln_in_b, part, bsum,
                                                  murs, slots, w_hh, b_hh, gg);
        k_gi<<<dim3(48, 4), 256, 0, stream>>>(part, bsum, ln_in_g, ln_in_b, Wiv, b_ih, gg);
        int last = (it == ITERS_ - 1);
        float* dst = last ? (float*)d_out : slots;
        k_p2<<<256, 512, 0, stream>>>(gg, slots, w1, b1, w2, b2, Mqk,
                                      ln_m_g, ln_m_b, ln_s_g, ln_s_b, dst, qk, last);
    }
}